// Round 3
// baseline (290.600 us; speedup 1.0000x reference)
//
#include <hip/hip_runtime.h>
#include <math.h>

// Problem constants: B=8, CIN=128, COUT=128, H=64, W=64, N=50000, NV=200000, M=800000
constexpr int CIN  = 128;
constexpr int COUT = 128;
constexpr int H    = 64;
constexpr int W    = 64;

// bf16 <-> f32 bit helpers (feat scratch is stored bf16 to halve footprint)
__device__ __forceinline__ float bf2f(unsigned short u) {
  union { unsigned i; float f; } c; c.i = (unsigned)u << 16; return c.f;
}
__device__ __forceinline__ unsigned short f2bf(float f) {
  union { float f; unsigned i; } c; c.f = f;
  unsigned x = c.i;
  unsigned r = x + 0x7fffu + ((x >> 16) & 1u);   // round-to-nearest-even
  return (unsigned short)(r >> 16);
}

// ---------------------------------------------------------------------------
// Kernel 1: 3x3 SAME conv, NCHW f32 input -> NHWC bf16 feat table
// Grid (16 tiles of 16x16, 8 batch, 4 channel-groups of 32); block 256.
// Thread computes 2x2 pixels x 8 out-channels, f32 accumulation.
// ---------------------------------------------------------------------------
__global__ __launch_bounds__(256, 2)
void conv3x3_kernel(const float* __restrict__ in, const float* __restrict__ wgt,
                    const float* __restrict__ bias, unsigned short* __restrict__ feat) {
  __shared__ float s_in[18 * 18];   // 16x16 tile + halo
  __shared__ float s_w[32 * 9];     // 32 out-channels x 9 taps

  const int tid  = threadIdx.x;
  const int b    = blockIdx.y;
  const int tile = blockIdx.x;
  const int h0   = (tile >> 2) * 16;
  const int w0   = (tile & 3) * 16;
  const int cg   = blockIdx.z;
  const int pix  = tid & 63;
  const int chid = tid >> 6;
  const int py0  = (pix >> 3) * 2;
  const int px0  = (pix & 7) * 2;
  const int co0  = cg * 32 + chid * 8;

  float acc[2][2][8];
#pragma unroll
  for (int dy = 0; dy < 2; ++dy)
#pragma unroll
    for (int dx = 0; dx < 2; ++dx)
#pragma unroll
      for (int k = 0; k < 8; ++k)
        acc[dy][dx][k] = bias[co0 + k];

  const float* inb = in + (size_t)b * CIN * H * W;

  for (int ci = 0; ci < CIN; ++ci) {
    const float* plane = inb + (size_t)ci * (H * W);
    // stage 18x18 input tile (zero-padded at borders): 324 entries, 256 threads
    for (int idx = tid; idx < 324; idx += 256) {
      int r = idx / 18, c = idx - r * 18;
      int gh = h0 + r - 1, gw = w0 + c - 1;
      float v = 0.f;
      if (gh >= 0 && gh < H && gw >= 0 && gw < W) v = plane[gh * W + gw];
      s_in[idx] = v;
    }
    // stage 32x9 weights: 288 entries, 256 threads -> strided loop (BUGFIX:
    // previous `if (tid < 288)` left s_w[252..287] uninitialized)
    for (int idx = tid; idx < 288; idx += 256) {
      int k = idx / 9, q = idx - k * 9;
      s_w[idx] = wgt[(size_t)(cg * 32 + k) * (CIN * 9) + ci * 9 + q];
    }
    __syncthreads();

    float rin[4][4];
#pragma unroll
    for (int r = 0; r < 4; ++r)
#pragma unroll
      for (int c = 0; c < 4; ++c)
        rin[r][c] = s_in[(py0 + r) * 18 + (px0 + c)];

#pragma unroll
    for (int k = 0; k < 8; ++k) {
      float wv[9];
#pragma unroll
      for (int q = 0; q < 9; ++q) wv[q] = s_w[(chid * 8 + k) * 9 + q];
#pragma unroll
      for (int ky = 0; ky < 3; ++ky)
#pragma unroll
        for (int kx = 0; kx < 3; ++kx) {
          float wq = wv[ky * 3 + kx];
#pragma unroll
          for (int dy = 0; dy < 2; ++dy)
#pragma unroll
            for (int dx = 0; dx < 2; ++dx)
              acc[dy][dx][k] = fmaf(rin[dy + ky][dx + kx], wq, acc[dy][dx][k]);
        }
    }
    __syncthreads();
  }

  // write NHWC bf16 feat: 8 channels = 16 bytes per pixel per thread
#pragma unroll
  for (int dy = 0; dy < 2; ++dy)
#pragma unroll
    for (int dx = 0; dx < 2; ++dx) {
      int h = h0 + py0 + dy, w = w0 + px0 + dx;
      size_t p = ((size_t)b * (H * W) + (size_t)h * W + w) * COUT + co0;
      union { unsigned short u[8]; float4 v; } pk;
#pragma unroll
      for (int k = 0; k < 8; ++k) pk.u[k] = f2bf(acc[dy][dx][k]);
      *reinterpret_cast<float4*>(feat + p) = pk.v;   // co0 % 8 == 0 -> 16B aligned
    }
}

// ---------------------------------------------------------------------------
// Kernel 2: fused gather + nested CSR max + add. One wave per 3D point.
// Pixels of point n = [aptr[vptr[n]], aptr[vptr[n+1]]).
// Empty view segments contribute 0 to the point max; empty points give 0.
// Each lane owns 2 channels. x_3d/out are f32; feat is bf16.
// ---------------------------------------------------------------------------
__global__ __launch_bounds__(256, 4)
void pool_kernel(const unsigned short* __restrict__ feat, const float* __restrict__ x3d,
                 const int* __restrict__ pix_idx, const int* __restrict__ aptr,
                 const int* __restrict__ vptr, float* __restrict__ out, int N) {
  int n = blockIdx.x * 4 + (threadIdx.x >> 6);
  if (n >= N) return;
  int lane = threadIdx.x & 63;

  int v0 = vptr[n], v1 = vptr[n + 1];
  int p0 = aptr[v0], p1 = aptr[v1];

  // any empty view segment inside [v0, v1)?
  bool empty_view = false;
  for (int v = v0 + lane; v < v1; v += 64)
    if (aptr[v] == aptr[v + 1]) empty_view = true;
  empty_view = __any(empty_view);

  float ax = -INFINITY, ay = -INFINITY;
  const unsigned short* fb = feat + lane * 2;

  int p = p0;
  for (; p + 3 < p1; p += 4) {
    int r0 = pix_idx[p], r1 = pix_idx[p + 1], r2 = pix_idx[p + 2], r3 = pix_idx[p + 3];
    ushort2 f0 = *reinterpret_cast<const ushort2*>(fb + (size_t)r0 * COUT);
    ushort2 f1 = *reinterpret_cast<const ushort2*>(fb + (size_t)r1 * COUT);
    ushort2 f2 = *reinterpret_cast<const ushort2*>(fb + (size_t)r2 * COUT);
    ushort2 f3 = *reinterpret_cast<const ushort2*>(fb + (size_t)r3 * COUT);
    ax = fmaxf(ax, fmaxf(fmaxf(bf2f(f0.x), bf2f(f1.x)), fmaxf(bf2f(f2.x), bf2f(f3.x))));
    ay = fmaxf(ay, fmaxf(fmaxf(bf2f(f0.y), bf2f(f1.y)), fmaxf(bf2f(f2.y), bf2f(f3.y))));
  }
  for (; p < p1; ++p) {
    int r = pix_idx[p];
    ushort2 f = *reinterpret_cast<const ushort2*>(fb + (size_t)r * COUT);
    ax = fmaxf(ax, bf2f(f.x));
    ay = fmaxf(ay, bf2f(f.y));
  }

  float vx, vy;
  if (v1 == v0) {
    vx = 0.f; vy = 0.f;                        // point with no views -> 0
  } else {
    if (empty_view) { ax = fmaxf(ax, 0.f); ay = fmaxf(ay, 0.f); }
    vx = ax; vy = ay;                          // all-views-empty: -inf folded to 0 above
  }

  size_t o = (size_t)n * COUT + lane * 2;
  float2 xv = *reinterpret_cast<const float2*>(x3d + o);
  float2 r = make_float2(xv.x + vx, xv.y + vy);
  *reinterpret_cast<float2*>(out + o) = r;
}

extern "C" void kernel_launch(void* const* d_in, const int* in_sizes, int n_in,
                              void* d_out, int out_size, void* d_ws, size_t ws_size,
                              hipStream_t stream) {
  const float* x3d     = (const float*)d_in[0];
  const float* mod_x   = (const float*)d_in[1];
  const float* conv_w  = (const float*)d_in[2];
  const float* conv_b  = (const float*)d_in[3];
  const int*   pix_idx = (const int*)d_in[4];
  const int*   aptr    = (const int*)d_in[5];
  const int*   vptr    = (const int*)d_in[6];
  float*       out     = (float*)d_out;

  // scratch: bf16 feat table [B*H*W=32768][COUT=128] = 8.39 MB
  unsigned short* feat = (unsigned short*)d_ws;

  dim3 g1(16, 8, 4);
  conv3x3_kernel<<<g1, 256, 0, stream>>>(mod_x, conv_w, conv_b, feat);

  int N = in_sizes[6] - 1;   // view_ptr has N+1 entries
  pool_kernel<<<(N + 3) / 4, 256, 0, stream>>>(feat, x3d, pix_idx, aptr, vptr, out, N);
}

// Round 4
// 93.813 us; speedup vs baseline: 3.0976x; 3.0976x over previous
//
#include <hip/hip_runtime.h>
#include <math.h>

// Problem constants: B=8, CIN=128, COUT=128, H=64, W=64, N=50000, NV=200000, M=800000
constexpr int CIN  = 128;
constexpr int COUT = 128;
constexpr int H    = 64;
constexpr int W    = 64;

typedef __attribute__((ext_vector_type(8))) short short8;   // 8 bf16 (4 VGPR)
typedef __attribute__((ext_vector_type(4))) float f32x4;

__device__ __forceinline__ float bf2f(unsigned short u) {
  union { unsigned i; float f; } c; c.i = (unsigned)u << 16; return c.f;
}
__device__ __forceinline__ unsigned short f2bf(float f) {
  union { float f; unsigned i; } c; c.f = f;
  unsigned x = c.i;
  unsigned r = x + 0x7fffu + ((x >> 16) & 1u);   // RNE
  return (unsigned short)(r >> 16);
}

#define GLOAD_LDS16(g, l) __builtin_amdgcn_global_load_lds( \
  (const __attribute__((address_space(1))) unsigned int*)(g), \
  (__attribute__((address_space(3))) unsigned int*)(l), 16, 0, 0)

// ---------------------------------------------------------------------------
// Pre-kernel: conv_w f32 [co][ci][3][3] -> Wt2 bf16 [q][co][ci]  (k-major for
// the MFMA B-fragment: per-lane contiguous ci)
// ---------------------------------------------------------------------------
__global__ void wt_cast_kernel(const float* __restrict__ w, unsigned short* __restrict__ wt2) {
  int t = blockIdx.x * 256 + threadIdx.x;        // t = co*128 + ci, 16384 total
  if (t >= COUT * CIN) return;
  float v[9];
#pragma unroll
  for (int q = 0; q < 9; ++q) v[q] = w[(size_t)t * 9 + q];
#pragma unroll
  for (int q = 0; q < 9; ++q) wt2[q * (COUT * CIN) + t] = f2bf(v[q]);
}

// ---------------------------------------------------------------------------
// Conv 3x3 SAME as implicit GEMM on MFMA bf16.
// Block: one (batch b, image row h0): M = 64 pixels (the w dim) x N = 128 co.
// K = 9 taps x 128 ci (ci chunked by 64, K-step 32).
// 4 waves: wave_px = (wid>>1)*32, wave_co = (wid&1)*64; per wave M_rep=2,N_rep=4.
// sIn [3 rows][66 wp][64 ci] bf16, zero-padded wp=0,65; XOR-swizzled (T2).
// sW  [128 co][64 ci] bf16, XOR-swizzled, staged via global_load_lds with
// inverse-swizzled per-lane source (both-sides-or-neither rule).
// ---------------------------------------------------------------------------
__global__ __launch_bounds__(256, 2)
void conv_mfma_kernel(const float* __restrict__ in, const unsigned short* __restrict__ wt2,
                      const float* __restrict__ bias, unsigned short* __restrict__ feat) {
  __shared__ __align__(16) unsigned short sIn[3 * 66 * 64];  // 25344 B
  __shared__ __align__(16) unsigned short sW[128 * 64];      // 16384 B

  const int tid  = threadIdx.x;
  const int lane = tid & 63;
  const int wid  = tid >> 6;
  const int h0   = blockIdx.x;     // 0..63
  const int b    = blockIdx.y;     // 0..7
  const int wave_px = (wid >> 1) * 32;
  const int wave_co = (wid & 1) * 64;
  const int l15  = lane & 15;
  const int kk   = lane >> 4;      // 0..3 k-subblock

  // byte strides: sIn row rr stride 8448 (=66*64*2), wp stride 128; sW co stride 128
  char* sInc = (char*)sIn;
  char* sWc  = (char*)sW;

  f32x4 acc[2][4];
#pragma unroll
  for (int m = 0; m < 2; ++m)
#pragma unroll
    for (int n = 0; n < 4; ++n) acc[m][n] = (f32x4){0.f, 0.f, 0.f, 0.f};

  float bv[4];
#pragma unroll
  for (int n = 0; n < 4; ++n) bv[n] = bias[wave_co + n * 16 + l15];

  // zero the pad columns wp=0 and wp=65 (swizzled addresses), once
  for (int i = tid; i < 3 * 64 * 2; i += 256) {
    int rr = i >> 7, rem = i & 127;
    int wp = (rem & 1) ? 65 : 0, ci = rem >> 1;
    int byte = rr * 8448 + wp * 128 + ci * 2;
    byte ^= ((wp & 7) << 4);
    *(unsigned short*)(sInc + byte) = 0;
  }

  // precompute sW staging: 4 rounds of global_load_lds(16B) per thread
  // linear dst d0 = i*4096 + wid*1024 + lane*16 ; content = inverse-swizzled src
  int swd[4], swsrc[4];
#pragma unroll
  for (int i = 0; i < 4; ++i) {
    int d0 = i * 4096 + wid * 1024 + lane * 16;
    int co = d0 >> 7;
    swd[i]   = d0;
    swsrc[i] = co * 256 + ((d0 & 127) ^ ((co & 7) << 4));  // + chunk*128 + q*32768 later
  }
  const char* wt2c = (const char*)wt2;

  for (int chunk = 0; chunk < 2; ++chunk) {
    __syncthreads();   // prior readers of sIn/sW done before overwrite
    // ---- stage input: rows h0-1..h0+1, 64 ci of this chunk, f32 -> bf16 swizzled
    if (tid < 192) {
      int rr = tid >> 6, cil = tid & 63;
      int ci = cil + chunk * 64;
      int h  = h0 + rr - 1;
      bool valid = (h >= 0) && (h < H);
      const float* src = in + (((size_t)b * CIN + ci) * H + (valid ? h : 0)) * W;
      int base = rr * 8448 + cil * 2;
#pragma unroll
      for (int j = 0; j < 16; ++j) {
        float4 v = valid ? *reinterpret_cast<const float4*>(src + j * 4)
                         : make_float4(0.f, 0.f, 0.f, 0.f);
        const float* ve = (const float*)&v;
#pragma unroll
        for (int e = 0; e < 4; ++e) {
          int wp = j * 4 + e + 1;
          int byte = (base + wp * 128) ^ ((wp & 7) << 4);
          *(unsigned short*)(sInc + byte) = f2bf(ve[e]);
        }
      }
    }

    for (int q = 0; q < 9; ++q) {
      if (q) __syncthreads();   // prior MFMA reads of sW done (q=0 covered above)
      // ---- stage sW for (q, chunk): 16 KB via global_load_lds
      const char* wq = wt2c + q * (COUT * CIN * 2) + chunk * 128;
#pragma unroll
      for (int i = 0; i < 4; ++i)
        GLOAD_LDS16(wq + swsrc[i], sWc + swd[i]);
      __syncthreads();          // drains vmcnt + lgkm (input ds_writes for q=0 too)

      const int ky = q / 3, kx = q % 3;
#pragma unroll
      for (int ks = 0; ks < 2; ++ks) {
        const int cil2 = ks * 64 + kk * 16;   // byte offset of this lane's k-slice
        short8 af[2];
#pragma unroll
        for (int m = 0; m < 2; ++m) {
          int wp = wave_px + m * 16 + l15 + kx;          // px + kx, pad-shifted
          int byte = (ky * 8448 + wp * 128 + cil2) ^ ((wp & 7) << 4);
          af[m] = *(const short8*)(sInc + byte);
        }
        short8 bf[4];
#pragma unroll
        for (int n = 0; n < 4; ++n) {
          int co = wave_co + n * 16 + l15;
          int byte = (co * 128 + cil2) ^ ((co & 7) << 4);
          bf[n] = *(const short8*)(sWc + byte);
        }
#pragma unroll
        for (int m = 0; m < 2; ++m)
#pragma unroll
          for (int n = 0; n < 4; ++n)
            acc[m][n] = __builtin_amdgcn_mfma_f32_16x16x32_bf16(af[m], bf[n], acc[m][n], 0, 0, 0);
      }
    }
  }

  // ---- epilogue: bias add, bf16 round, NHWC feat write
  const size_t pbase = ((size_t)b * H + h0) * W;   // pixel index of w=0
#pragma unroll
  for (int m = 0; m < 2; ++m) {
#pragma unroll
    for (int r = 0; r < 4; ++r) {
      int px = wave_px + m * 16 + (lane >> 4) * 4 + r;
      unsigned short* dst = feat + (pbase + px) * COUT;
#pragma unroll
      for (int n = 0; n < 4; ++n) {
        int co = wave_co + n * 16 + l15;
        dst[co] = f2bf(acc[m][n][r] + bv[n]);
      }
    }
  }
}

// ---------------------------------------------------------------------------
// Fused gather + nested CSR max + add. One wave per 3D point. (round-3, passed)
// ---------------------------------------------------------------------------
__global__ __launch_bounds__(256, 4)
void pool_kernel(const unsigned short* __restrict__ feat, const float* __restrict__ x3d,
                 const int* __restrict__ pix_idx, const int* __restrict__ aptr,
                 const int* __restrict__ vptr, float* __restrict__ out, int N) {
  int n = blockIdx.x * 4 + (threadIdx.x >> 6);
  if (n >= N) return;
  int lane = threadIdx.x & 63;

  int v0 = vptr[n], v1 = vptr[n + 1];
  int p0 = aptr[v0], p1 = aptr[v1];

  bool empty_view = false;
  for (int v = v0 + lane; v < v1; v += 64)
    if (aptr[v] == aptr[v + 1]) empty_view = true;
  empty_view = __any(empty_view);

  float ax = -INFINITY, ay = -INFINITY;
  const unsigned short* fb = feat + lane * 2;

  int p = p0;
  for (; p + 3 < p1; p += 4) {
    int r0 = pix_idx[p], r1 = pix_idx[p + 1], r2 = pix_idx[p + 2], r3 = pix_idx[p + 3];
    ushort2 f0 = *reinterpret_cast<const ushort2*>(fb + (size_t)r0 * COUT);
    ushort2 f1 = *reinterpret_cast<const ushort2*>(fb + (size_t)r1 * COUT);
    ushort2 f2 = *reinterpret_cast<const ushort2*>(fb + (size_t)r2 * COUT);
    ushort2 f3 = *reinterpret_cast<const ushort2*>(fb + (size_t)r3 * COUT);
    ax = fmaxf(ax, fmaxf(fmaxf(bf2f(f0.x), bf2f(f1.x)), fmaxf(bf2f(f2.x), bf2f(f3.x))));
    ay = fmaxf(ay, fmaxf(fmaxf(bf2f(f0.y), bf2f(f1.y)), fmaxf(bf2f(f2.y), bf2f(f3.y))));
  }
  for (; p < p1; ++p) {
    int r = pix_idx[p];
    ushort2 f = *reinterpret_cast<const ushort2*>(fb + (size_t)r * COUT);
    ax = fmaxf(ax, bf2f(f.x));
    ay = fmaxf(ay, bf2f(f.y));
  }

  float vx, vy;
  if (v1 == v0) {
    vx = 0.f; vy = 0.f;
  } else {
    if (empty_view) { ax = fmaxf(ax, 0.f); ay = fmaxf(ay, 0.f); }
    vx = ax; vy = ay;
  }

  size_t o = (size_t)n * COUT + lane * 2;
  float2 xv = *reinterpret_cast<const float2*>(x3d + o);
  float2 r = make_float2(xv.x + vx, xv.y + vy);
  *reinterpret_cast<float2*>(out + o) = r;
}

extern "C" void kernel_launch(void* const* d_in, const int* in_sizes, int n_in,
                              void* d_out, int out_size, void* d_ws, size_t ws_size,
                              hipStream_t stream) {
  const float* x3d     = (const float*)d_in[0];
  const float* mod_x   = (const float*)d_in[1];
  const float* conv_w  = (const float*)d_in[2];
  const float* conv_b  = (const float*)d_in[3];
  const int*   pix_idx = (const int*)d_in[4];
  const int*   aptr    = (const int*)d_in[5];
  const int*   vptr    = (const int*)d_in[6];
  float*       out     = (float*)d_out;

  // ws layout: feat bf16 [32768][128] = 8388608 B, then Wt2 bf16 [9][128][128] = 294912 B
  unsigned short* feat = (unsigned short*)d_ws;
  unsigned short* wt2  = (unsigned short*)((char*)d_ws + 8388608);

  wt_cast_kernel<<<64, 256, 0, stream>>>(conv_w, wt2);

  dim3 gc(64, 8);   // h0 x b
  conv_mfma_kernel<<<gc, 256, 0, stream>>>(mod_x, wt2, conv_b, feat);

  int N = in_sizes[6] - 1;
  pool_kernel<<<(N + 3) / 4, 256, 0, stream>>>(feat, x3d, pix_idx, aptr, vptr, out, N);
}

// Round 5
// 75.331 us; speedup vs baseline: 3.8576x; 1.2453x over previous
//
#include <hip/hip_runtime.h>
#include <math.h>

// Problem constants: B=8, CIN=128, COUT=128, H=64, W=64, N=50000, NV=200000, M=800000
constexpr int CIN  = 128;
constexpr int COUT = 128;
constexpr int H    = 64;
constexpr int W    = 64;

typedef __attribute__((ext_vector_type(8))) short short8;   // 8 bf16 (4 VGPR)
typedef __attribute__((ext_vector_type(4))) float f32x4;

__device__ __forceinline__ float bf2f(unsigned short u) {
  union { unsigned i; float f; } c; c.i = (unsigned)u << 16; return c.f;
}
__device__ __forceinline__ float ubits(unsigned u) {
  union { unsigned i; float f; } c; c.i = u; return c.f;
}
__device__ __forceinline__ unsigned short f2bf(float f) {
  union { float f; unsigned i; } c; c.f = f;
  unsigned x = c.i;
  unsigned r = x + 0x7fffu + ((x >> 16) & 1u);   // RNE
  return (unsigned short)(r >> 16);
}

#define GLOAD_LDS16(g, l) __builtin_amdgcn_global_load_lds( \
  (const __attribute__((address_space(1))) unsigned int*)(g), \
  (__attribute__((address_space(3))) unsigned int*)(l), 16, 0, 0)

// ---------------------------------------------------------------------------
// Prep: (a) conv_w f32 [co][ci][3][3] -> Wt2 bf16 [q][co][ci] (k-major);
//       (b) per-point CSR meta: p0, p1, zero-fold flag
//           zfold = (no views) || (any empty view in range)
// ---------------------------------------------------------------------------
__global__ void prep_kernel(const float* __restrict__ w, unsigned short* __restrict__ wt2,
                            const int* __restrict__ aptr, const int* __restrict__ vptr,
                            int2* __restrict__ meta, int N) {
  int t = blockIdx.x * 256 + threadIdx.x;
  if (t < COUT * CIN) {
    float v[9];
#pragma unroll
    for (int q = 0; q < 9; ++q) v[q] = w[(size_t)t * 9 + q];
#pragma unroll
    for (int q = 0; q < 9; ++q) wt2[q * (COUT * CIN) + t] = f2bf(v[q]);
  }
  if (t < N) {
    int v0 = vptr[t], v1 = vptr[t + 1];
    int p0 = aptr[v0], p1 = aptr[v1];
    int e = (v1 == v0) ? 1 : 0;
    int prev = p0;
    for (int v = v0 + 1; v <= v1; ++v) {   // detect empty view segments
      int a = aptr[v];
      if (a == prev) e = 1;
      prev = a;
    }
    meta[t] = make_int2(p0, p1 | (e << 30));
  }
}

// ---------------------------------------------------------------------------
// Conv 3x3 SAME as implicit GEMM on MFMA bf16 (round-4, passed).
// ---------------------------------------------------------------------------
__global__ __launch_bounds__(256, 2)
void conv_mfma_kernel(const float* __restrict__ in, const unsigned short* __restrict__ wt2,
                      const float* __restrict__ bias, unsigned short* __restrict__ feat) {
  __shared__ __align__(16) unsigned short sIn[3 * 66 * 64];  // 25344 B
  __shared__ __align__(16) unsigned short sW[128 * 64];      // 16384 B

  const int tid  = threadIdx.x;
  const int lane = tid & 63;
  const int wid  = tid >> 6;
  const int h0   = blockIdx.x;
  const int b    = blockIdx.y;
  const int wave_px = (wid >> 1) * 32;
  const int wave_co = (wid & 1) * 64;
  const int l15  = lane & 15;
  const int kk   = lane >> 4;

  char* sInc = (char*)sIn;
  char* sWc  = (char*)sW;

  f32x4 acc[2][4];
#pragma unroll
  for (int m = 0; m < 2; ++m)
#pragma unroll
    for (int n = 0; n < 4; ++n) acc[m][n] = (f32x4){0.f, 0.f, 0.f, 0.f};

  float bv[4];
#pragma unroll
  for (int n = 0; n < 4; ++n) bv[n] = bias[wave_co + n * 16 + l15];

  for (int i = tid; i < 3 * 64 * 2; i += 256) {   // zero pad columns wp=0,65
    int rr = i >> 7, rem = i & 127;
    int wp = (rem & 1) ? 65 : 0, ci = rem >> 1;
    int byte = rr * 8448 + wp * 128 + ci * 2;
    byte ^= ((wp & 7) << 4);
    *(unsigned short*)(sInc + byte) = 0;
  }

  int swd[4], swsrc[4];
#pragma unroll
  for (int i = 0; i < 4; ++i) {
    int d0 = i * 4096 + wid * 1024 + lane * 16;
    int co = d0 >> 7;
    swd[i]   = d0;
    swsrc[i] = co * 256 + ((d0 & 127) ^ ((co & 7) << 4));
  }
  const char* wt2c = (const char*)wt2;

  for (int chunk = 0; chunk < 2; ++chunk) {
    __syncthreads();
    if (tid < 192) {   // stage input rows h0-1..h0+1, 64 ci, f32 -> bf16 swizzled
      int rr = tid >> 6, cil = tid & 63;
      int ci = cil + chunk * 64;
      int h  = h0 + rr - 1;
      bool valid = (h >= 0) && (h < H);
      const float* src = in + (((size_t)b * CIN + ci) * H + (valid ? h : 0)) * W;
      int base = rr * 8448 + cil * 2;
#pragma unroll
      for (int j = 0; j < 16; ++j) {
        float4 v = valid ? *reinterpret_cast<const float4*>(src + j * 4)
                         : make_float4(0.f, 0.f, 0.f, 0.f);
        const float* ve = (const float*)&v;
#pragma unroll
        for (int e = 0; e < 4; ++e) {
          int wp = j * 4 + e + 1;
          int byte = (base + wp * 128) ^ ((wp & 7) << 4);
          *(unsigned short*)(sInc + byte) = f2bf(ve[e]);
        }
      }
    }

    for (int q = 0; q < 9; ++q) {
      if (q) __syncthreads();
      const char* wq = wt2c + q * (COUT * CIN * 2) + chunk * 128;
#pragma unroll
      for (int i = 0; i < 4; ++i)
        GLOAD_LDS16(wq + swsrc[i], sWc + swd[i]);
      __syncthreads();

      const int ky = q / 3, kx = q % 3;
#pragma unroll
      for (int ks = 0; ks < 2; ++ks) {
        const int cil2 = ks * 64 + kk * 16;
        short8 af[2];
#pragma unroll
        for (int m = 0; m < 2; ++m) {
          int wp = wave_px + m * 16 + l15 + kx;
          int byte = (ky * 8448 + wp * 128 + cil2) ^ ((wp & 7) << 4);
          af[m] = *(const short8*)(sInc + byte);
        }
        short8 bf[4];
#pragma unroll
        for (int n = 0; n < 4; ++n) {
          int co = wave_co + n * 16 + l15;
          int byte = (co * 128 + cil2) ^ ((co & 7) << 4);
          bf[n] = *(const short8*)(sWc + byte);
        }
#pragma unroll
        for (int m = 0; m < 2; ++m)
#pragma unroll
          for (int n = 0; n < 4; ++n)
            acc[m][n] = __builtin_amdgcn_mfma_f32_16x16x32_bf16(af[m], bf[n], acc[m][n], 0, 0, 0);
      }
    }
  }

  const size_t pbase = ((size_t)b * H + h0) * W;
#pragma unroll
  for (int m = 0; m < 2; ++m) {
#pragma unroll
    for (int r = 0; r < 4; ++r) {
      int px = wave_px + m * 16 + (lane >> 4) * 4 + r;
      unsigned short* dst = feat + (pbase + px) * COUT;
#pragma unroll
      for (int n = 0; n < 4; ++n) {
        int co = wave_co + n * 16 + l15;
        dst[co] = f2bf(acc[m][n][r] + bv[n]);
      }
    }
  }
}

// ---------------------------------------------------------------------------
// Pool: one wave per point. lane = (pixel slot lane>>4, channel group lane&15).
// Per VMEM instruction: 4 pixels x 128 ch (16 B/lane). Tail pixels clamped to
// a valid row and masked to bf16 -inf. Final shfl_xor reduce over slots.
// ---------------------------------------------------------------------------
__global__ __launch_bounds__(256, 8)
void pool_kernel(const unsigned short* __restrict__ feat, const float* __restrict__ x3d,
                 const int* __restrict__ pix_idx, const int2* __restrict__ meta,
                 float* __restrict__ out, int N) {
  int n = blockIdx.x * 4 + (threadIdx.x >> 6);
  if (n >= N) return;
  const int lane = threadIdx.x & 63;
  const int slot = lane >> 4;
  const int l15  = lane & 15;

  const int2 mm = meta[n];
  const int p0 = mm.x;
  const int p1 = mm.y & 0x3FFFFFFF;
  const bool zfold = (mm.y & 0x40000000) != 0;

  const size_t o = (size_t)n * COUT + l15 * 8 + slot * 2;
  const float2 xv = *reinterpret_cast<const float2*>(x3d + o);   // hoisted

  float acc[8];
#pragma unroll
  for (int j = 0; j < 8; ++j) acc[j] = -INFINITY;

  const char* fb = (const char*)feat + l15 * 16;
  const int last = p1 - 1;

  for (int g = p0; g < p1; g += 8) {
    int pp0 = g + slot, pp1 = g + 4 + slot;
    int i0 = pix_idx[min(pp0, last)];
    int i1 = pix_idx[min(pp1, last)];
    uint4 a = *reinterpret_cast<const uint4*>(fb + (size_t)i0 * 256);
    uint4 b = *reinterpret_cast<const uint4*>(fb + (size_t)i1 * 256);
    if (pp0 > last) { a.x = a.y = a.z = a.w = 0xFF80FF80u; }   // bf16 -inf pair
    if (pp1 > last) { b.x = b.y = b.z = b.w = 0xFF80FF80u; }
    const unsigned* aw = (const unsigned*)&a;
    const unsigned* bw = (const unsigned*)&b;
#pragma unroll
    for (int j = 0; j < 4; ++j) {
      acc[2*j]   = fmaxf(acc[2*j],   fmaxf(ubits(aw[j] << 16),        ubits(bw[j] << 16)));
      acc[2*j+1] = fmaxf(acc[2*j+1], fmaxf(ubits(aw[j] & 0xFFFF0000u), ubits(bw[j] & 0xFFFF0000u)));
    }
  }

  // reduce over the 4 pixel slots (lanes l15, l15+16, l15+32, l15+48)
#pragma unroll
  for (int j = 0; j < 8; ++j) {
    acc[j] = fmaxf(acc[j], __shfl_xor(acc[j], 16, 64));
    acc[j] = fmaxf(acc[j], __shfl_xor(acc[j], 32, 64));
  }
  if (zfold) {
#pragma unroll
    for (int j = 0; j < 8; ++j) acc[j] = fmaxf(acc[j], 0.f);
  }
  // p1==p0 => loop skipped, acc=-inf, zfold guaranteed true -> 0

  float2 r = make_float2(xv.x + acc[slot * 2], xv.y + acc[slot * 2 + 1]);
  *reinterpret_cast<float2*>(out + o) = r;
}

extern "C" void kernel_launch(void* const* d_in, const int* in_sizes, int n_in,
                              void* d_out, int out_size, void* d_ws, size_t ws_size,
                              hipStream_t stream) {
  const float* x3d     = (const float*)d_in[0];
  const float* mod_x   = (const float*)d_in[1];
  const float* conv_w  = (const float*)d_in[2];
  const float* conv_b  = (const float*)d_in[3];
  const int*   pix_idx = (const int*)d_in[4];
  const int*   aptr    = (const int*)d_in[5];
  const int*   vptr    = (const int*)d_in[6];
  float*       out     = (float*)d_out;

  int N = in_sizes[6] - 1;   // view_ptr has N+1 entries

  // ws layout: feat bf16 [32768][128] = 8388608 B; Wt2 bf16 [9][128][128] = 294912 B;
  //            meta int2 [N] = 400000 B  (total ~9.08 MB)
  unsigned short* feat = (unsigned short*)d_ws;
  unsigned short* wt2  = (unsigned short*)((char*)d_ws + 8388608);
  int2*           meta = (int2*)((char*)d_ws + 8388608 + 294912);

  prep_kernel<<<(N + 255) / 256, 256, 0, stream>>>(conv_w, wt2, aptr, vptr, meta, N);

  dim3 gc(64, 8);   // h0 x b
  conv_mfma_kernel<<<gc, 256, 0, stream>>>(mod_x, wt2, conv_b, feat);

  pool_kernel<<<(N + 3) / 4, 256, 0, stream>>>(feat, x3d, pix_idx, meta, out, N);
}